// Round 7
// baseline (130.876 us; speedup 1.0000x reference)
//
#include <hip/hip_runtime.h>

// Problem constants (fixed by setup_inputs in the reference).
#define BS 32
#define NG 64            // num_gt
#define NP 8400          // num_priors
#define NTOPK 9
#define NUM_CLASSES 80
#define NCAND 27         // 3 levels * TOPK

#define TILE 128         // priors per writer block (66 tiles: 2 generations/CU)
#define NTILE 66         // ceil(8400/128)

// ---------------------------------------------------------------------------
// Kernel 1 (R6-verified, VERBATIM): one WAVE per (b, g); 512 blocks x 256.
// Lanes 0-24 own the 5x5 window; 9 rounds of 5-step __shfl_xor butterfly min
// over packed key (dist_bits<<32|idx) == lax.top_k order; slot-order sum +
// ddof=1 variance -> thr bit-exact. Output: per-(b,g) list of 27 u32 slots
// (prior idx if slot passes pad/thr/center-in-gt, else 0xFFFFFFFF). All 27
// slots written unconditionally -> workspace needs no init, no atomics.
// ---------------------------------------------------------------------------
__device__ __forceinline__ unsigned long long wave_min_u64_32(unsigned long long k) {
    #pragma unroll
    for (int off = 1; off < 32; off <<= 1) {
        unsigned long long o = __shfl_xor(k, off, 64);
        k = (o < k) ? o : k;
    }
    return k;   // lanes 0-31 hold min over lanes 0-31 (keys live in 0-24)
}

__global__ __launch_bounds__(256) void k_candidates(
    const float4* __restrict__ gt_bboxes,    // (BS*NG)
    const float*  __restrict__ pad_flag,     // (BS*NG)
    unsigned int* __restrict__ cand)         // (BS*NG, NCAND) u32 slots
{
    const int bg   = (blockIdx.x * 256 + threadIdx.x) >> 6;  // wave id = (b,g)
    const int lane = threadIdx.x & 63;

    const float4 gt  = gt_bboxes[bg];        // wave-uniform broadcast load
    const float  pad = pad_flag[bg];
    const float  gcx = (gt.x + gt.z) * 0.5f;
    const float  gcy = (gt.y + gt.w) * 0.5f;
    const float  garea = (gt.z - gt.x) * (gt.w - gt.y);

    const float lvl_s[3] = {8.0f, 16.0f, 32.0f};
    const int   lvl_n[3] = {80, 40, 20};
    const int   lvl_b[3] = {0, 6400, 8000};

    float ov[NCAND];    // candidate IoUs, slot order (registers: static idx)
    int   ixs[NCAND];   // candidate prior indices
    float sum = 0.0f;

    const int dy5 = lane / 5;          // cell owned by this lane (lane<25)
    const int dx5 = lane - dy5 * 5;

    #pragma unroll
    for (int L = 0; L < 3; ++L) {
        const float s    = lvl_s[L];
        const int   n    = lvl_n[L];
        const int   base = lvl_b[L];

        int wx = (int)floorf(gcx / s) - 2;
        int wy = (int)floorf(gcy / s) - 2;
        wx = min(max(wx, 0), n - 5);
        wy = min(max(wy, 0), n - 5);

        // lane-parallel key build over the 5x5 window
        unsigned long long key = ~0ull;
        if (lane < 25) {
            const int   iy  = wy + dy5;
            const int   ix  = wx + dx5;
            const float py  = ((float)iy + 0.5f) * s;
            const float px  = ((float)ix + 0.5f) * s;
            const float ddx = gcx - px;
            const float ddy = gcy - py;
            const float d   = sqrtf(ddx * ddx + ddy * ddy);
            key = ((unsigned long long)__float_as_uint(d) << 32) |
                  (unsigned int)(base + iy * n + ix);
        }

        const float hx = s * 2.5f;
        #pragma unroll
        for (int q = 0; q < NTOPK; ++q) {
            const unsigned long long m = wave_min_u64_32(key);
            if (key == m) key = ~0ull;           // unique keys: one lane drops out

            // emit slot (ascending dist = lax.top_k order): IoU on all lanes
            const int slot = L * NTOPK + q;
            const int idx  = (int)(m & 0xffffffffu);
            const int rel  = idx - base;
            const int iy   = rel / n;            // n compile-time constant
            const int ix   = rel - iy * n;
            const float px = ((float)ix + 0.5f) * s;
            const float py = ((float)iy + 0.5f) * s;
            const float px0 = px - hx, py0 = py - hx;
            const float px1 = px + hx, py1 = py + hx;
            float lx = fmaxf(gt.x, px0), ly = fmaxf(gt.y, py0);
            float rx = fminf(gt.z, px1), ry = fminf(gt.w, py1);
            float w = fmaxf(rx - lx, 0.0f), h = fmaxf(ry - ly, 0.0f);
            float ovl = w * h;
            float parea = (px1 - px0) * (py1 - py0);
            float o = ovl / fmaxf(garea + parea - ovl, 1e-6f);  // EPS_OVERLAPS
            ov[slot]  = o;
            ixs[slot] = idx;
            sum += o;                             // slot-order accumulation
        }
    }

    const float mean = sum / (float)NCAND;
    float var = 0.0f;
    #pragma unroll
    for (int i = 0; i < NCAND; ++i) {
        float d = ov[i] - mean;
        var += d * d;
    }
    const float thr = mean + sqrtf(var / (float)(NCAND - 1));   // std ddof=1

    // per-slot pass condition (identical to the verified atomicOr guard);
    // lane i keeps slot i's verdict, then lanes 0-26 store coalesced.
    unsigned int myval = 0xFFFFFFFFu;
    if (pad > 0.0f) {
        #pragma unroll
        for (int i = 0; i < NCAND; ++i) {
            bool pass = false;
            if (ov[i] > thr) {
                const int   L    = i / NTOPK;     // static per unrolled i
                const float s    = lvl_s[L];
                const int   n    = lvl_n[L];
                const int   base = lvl_b[L];
                const int idx = ixs[i];
                const int rel = idx - base;
                const int iy  = rel / n;
                const int ix  = rel - iy * n;
                const float px = ((float)ix + 0.5f) * s;  // == cell center (exact)
                const float py = ((float)iy + 0.5f) * s;
                // prior center strictly inside gt box (> 1e-9)
                float mm = fminf(fminf(px - gt.x, py - gt.y),
                                 fminf(gt.z - px, gt.w - py));
                pass = (mm > 1e-9f);
            }
            if (lane == i && pass) myval = (unsigned int)ixs[i];
        }
    }
    if (lane < NCAND) cand[(size_t)bg * NCAND + lane] = myval;
}

// ---------------------------------------------------------------------------
// Kernel 2: writer, 66x32 blocks x 256, 128-prior tiles.
// R6 ran 33x32 (4 blocks/CU = ONE generation): the invert+resolve prefix
// added serially to the store phase. 2112 blocks -> ~2 generations/CU, so
// late blocks' prefixes overlap early blocks' streaming stores.
// Invert is prefiltered: thread (g = t>>2, L = t&3, L<3) recomputes gt g's
// level-L window span from s_gt and reads its 9 cand entries ONLY if the
// span intersects this tile (conservative superset test -> identical (g,p)
// OR-set -> masks bit-identical to R6). Resolve + stores VERBATIM from the
// R1/R6-verified bodies.
// ---------------------------------------------------------------------------
__global__ __launch_bounds__(256) void k_write(
    const float4* __restrict__ priors,
    const float4* __restrict__ gt_bboxes,
    const int*    __restrict__ gt_labels,
    const float4* __restrict__ pred_bboxes,
    const unsigned int* __restrict__ cand,
    float* __restrict__ out)
{
    __shared__ float4 s_gt[NG];
    __shared__ int    s_lab[NG];
    __shared__ unsigned long long s_pos[TILE];
    __shared__ int    s_plab[TILE];
    __shared__ float  s_piou[TILE];

    const int b   = blockIdx.y;
    const int tid = threadIdx.x;
    const int p0  = blockIdx.x * TILE;
    const int npr = min(TILE, NP - p0);        // 128, or 80 in the last tile

    if (tid < NG) {
        s_gt[tid]  = gt_bboxes[b * NG + tid];
        s_lab[tid] = gt_labels[b * NG + tid];
    }
    if (tid < TILE) s_pos[tid] = 0;
    __syncthreads();

    // ---- prefiltered invert: (g, L) per thread; skip non-intersecting ----
    {
        const int g    = tid >> 2;
        const int part = tid & 3;              // 0..2 = level, 3 = idle
        if (part < 3) {
            const float s    = (part == 0) ? 8.0f : (part == 1) ? 16.0f : 32.0f;
            const int   n    = (part == 0) ? 80   : (part == 1) ? 40    : 20;
            const int   base = (part == 0) ? 0    : (part == 1) ? 6400  : 8000;
            const float4 gt  = s_gt[g];
            const float  gcx = (gt.x + gt.z) * 0.5f;
            const float  gcy = (gt.y + gt.w) * 0.5f;
            int wx = min(max((int)floorf(gcx / s) - 2, 0), n - 5);
            int wy = min(max((int)floorf(gcy / s) - 2, 0), n - 5);
            const int minidx = base + wy * n + wx;            // window span
            const int maxidx = base + (wy + 4) * n + wx + 4;  // (conservative)
            if (maxidx >= p0 && minidx < p0 + npr) {
                const unsigned int* e =
                    cand + ((size_t)(b * NG + g)) * NCAND + part * NTOPK;
                #pragma unroll
                for (int k = 0; k < NTOPK; ++k) {
                    unsigned int rel = e[k] - (unsigned int)p0;  // wraps if miss
                    if (rel < (unsigned int)npr)
                        atomicOr(&s_pos[rel], 1ull << g);
                }
            }
        }
    }
    __syncthreads();

    // ---- resolve + labels/bbox/fg (verbatim R1/R6 semantics) ----
    if (tid < npr) {
        const int p = p0 + tid;
        const size_t bp = (size_t)b * NP + p;
        unsigned long long mask = s_pos[tid];
        int fg = __popcll(mask);
        int gidx = 0;

        if (fg > 1) {
            // conflict: argmax_g IoU(gt, prior_cell_box) over ALL gts, first
            // max wins (matches jnp.argmax(overlaps, axis=1) semantics).
            float4 pr = priors[p];
            float hx = pr.z * 2.5f, hy = pr.w * 2.5f;
            float px0 = pr.x - hx, py0 = pr.y - hy, px1 = pr.x + hx, py1 = pr.y + hy;
            float parea = (px1 - px0) * (py1 - py0);
            float best = -1.0f;
            for (int gg = 0; gg < NG; ++gg) {
                float4 gtb = s_gt[gg];
                float lx = fmaxf(gtb.x, px0), ly = fmaxf(gtb.y, py0);
                float rx = fminf(gtb.z, px1), ry = fminf(gtb.w, py1);
                float w = fmaxf(rx - lx, 0.0f), h = fmaxf(ry - ly, 0.0f);
                float ovl = w * h;
                float ga = (gtb.z - gtb.x) * (gtb.w - gtb.y);
                float v = ovl / fmaxf(ga + parea - ovl, 1e-6f);
                if (v > best) { best = v; gidx = gg; }
            }
        } else if (fg == 1) {
            gidx = __ffsll((unsigned long long)mask) - 1;
        }

        const bool   fgm = fg > 0;
        const float4 gtb = s_gt[gidx];   // gidx==0 for background (ref: argmax of zeros)
        const int  label = fgm ? s_lab[gidx] : NUM_CLASSES;
        float iou_w = 0.0f;

        if (fgm) {
            float4 pb = pred_bboxes[bp];
            float lx = fmaxf(gtb.x, pb.x), ly = fmaxf(gtb.y, pb.y);
            float rx = fminf(gtb.z, pb.z), ry = fminf(gtb.w, pb.w);
            float w = fmaxf(rx - lx, 0.0f), h = fmaxf(ry - ly, 0.0f);
            float ov = w * h;
            float ga = (gtb.z - gtb.x) * (gtb.w - gtb.y);
            float pa = (pb.z - pb.x) * (pb.w - pb.y);
            iou_w = ov / (ga + pa - ov + 1e-9f);          // EPS_YOLOV6
        }

        out[bp] = (float)label;                           // labels
        ((float4*)(out + (size_t)BS * NP))[bp] = gtb;     // bboxes
        out[(size_t)BS * NP * 85 + bp] = fgm ? 1.0f : 0.0f;  // fg_mask

        s_plab[tid] = label;
        s_piou[tid] = iou_w;
    }
    __syncthreads();

    // ---- scores: [p0*80, (p0+npr)*80) floats of batch b -> coalesced f4 ----
    const int nfl4 = npr * 20;
    float4* o4 = (float4*)(out + (size_t)BS * NP * 5 + ((size_t)b * NP + p0) * 80);
    for (int q = tid; q < nfl4; q += 256) {
        int pl   = q / 20;          // local prior
        int comp = q - pl * 20;     // float4 slot within the 80-class row
        int lab  = s_plab[pl];
        float iw = s_piou[pl];
        int dd = lab - comp * 4;
        float4 v;
        v.x = (dd == 0) ? iw : 0.0f;
        v.y = (dd == 1) ? iw : 0.0f;
        v.z = (dd == 2) ? iw : 0.0f;
        v.w = (dd == 3) ? iw : 0.0f;
        o4[q] = v;
    }
}

extern "C" void kernel_launch(void* const* d_in, const int* in_sizes, int n_in,
                              void* d_out, int out_size, void* d_ws, size_t ws_size,
                              hipStream_t stream) {
    const float4* pred_bboxes = (const float4*)d_in[0];  // (32,8400,4) f32
    const float4* priors      = (const float4*)d_in[1];  // (8400,4)    f32
    const int*    gt_labels   = (const int*)d_in[2];     // (32,64,1)   i32
    const float4* gt_bboxes   = (const float4*)d_in[3];  // (32,64,4)   f32
    const float*  pad_flag    = (const float*)d_in[4];   // (32,64,1)   f32
    // d_in[5] = num_level_priors (6400,1600,400) — static, hard-coded.

    unsigned int* cand = (unsigned int*)d_ws;   // 221 KB, fully overwritten

    // TWO regular dispatches, no memset (best measured structure, R6).
    k_candidates<<<dim3(BS * NG * 64 / 256), dim3(256), 0, stream>>>(
        gt_bboxes, pad_flag, cand);

    k_write<<<dim3(NTILE, BS), dim3(256), 0, stream>>>(
        priors, gt_bboxes, gt_labels, pred_bboxes, cand, (float*)d_out);
}

// Round 8
// 127.196 us; speedup vs baseline: 1.0289x; 1.0289x over previous
//
#include <hip/hip_runtime.h>

// Problem constants (fixed by setup_inputs in the reference).
#define BS 32
#define NG 64            // num_gt
#define NP 8400          // num_priors
#define NTOPK 9
#define NUM_CLASSES 80
#define NCAND 27         // 3 levels * TOPK

#define TILE 256         // writer tile (R6 layout — best measured)
#define NTILE 33         // ceil(8400/256)

// ---------------------------------------------------------------------------
// Kernel 1: one BLOCK per (b, g); 2048 blocks x 192 (3 waves = 3 levels).
// Change vs R6 (which was wave-per-(b,g), levels serial): each wave runs the
// VERBATIM verified 25-cell/5x5 butterfly pipeline for ONE level -> serial
// shfl chain is 9 rounds, not 27, and occupancy is 24 waves/CU, not 8.
// The 27 (ov, idx) pairs go to LDS; the slot-order sum (i=0..26 sequential,
// no fast-math -> FP order preserved) and ddof=1 variance reproduce the
// R6-verified thr bit-exactly. Threads 0-26 emit the per-slot verdicts with
// identical constants/arithmetic. Output format unchanged: 27 u32 slots per
// (b,g) (prior idx if pass, else 0xFFFFFFFF), fully overwritten, no init.
// ---------------------------------------------------------------------------
__device__ __forceinline__ unsigned long long wave_min_u64_32(unsigned long long k) {
    #pragma unroll
    for (int off = 1; off < 32; off <<= 1) {
        unsigned long long o = __shfl_xor(k, off, 64);
        k = (o < k) ? o : k;
    }
    return k;   // each 32-lane half holds the min over its half (keys in 0-24)
}

__global__ __launch_bounds__(192) void k_candidates(
    const float4* __restrict__ gt_bboxes,    // (BS*NG)
    const float*  __restrict__ pad_flag,     // (BS*NG)
    unsigned int* __restrict__ cand)         // (BS*NG, NCAND) u32 slots
{
    __shared__ float s_ov[NCAND];
    __shared__ int   s_ix[NCAND];

    const int bg   = blockIdx.x;             // (b,g)
    const int tid  = threadIdx.x;
    const int lane = tid & 63;
    const int L    = tid >> 6;               // wave id = level 0..2

    const float4 gt  = gt_bboxes[bg];        // uniform broadcast load
    const float  pad = pad_flag[bg];
    const float  gcx = (gt.x + gt.z) * 0.5f;
    const float  gcy = (gt.y + gt.w) * 0.5f;
    const float  garea = (gt.z - gt.x) * (gt.w - gt.y);

    const float s    = (L == 0) ? 8.0f : (L == 1) ? 16.0f : 32.0f;
    const int   n    = (L == 0) ? 80   : (L == 1) ? 40    : 20;
    const int   base = (L == 0) ? 0    : (L == 1) ? 6400  : 8000;

    int wx = min(max((int)floorf(gcx / s) - 2, 0), n - 5);
    int wy = min(max((int)floorf(gcy / s) - 2, 0), n - 5);

    // lane-parallel key build over this level's 5x5 window (verbatim)
    const int dy5 = lane / 5;
    const int dx5 = lane - dy5 * 5;
    unsigned long long key = ~0ull;
    if (lane < 25) {
        const int   iy  = wy + dy5;
        const int   ix  = wx + dx5;
        const float py  = ((float)iy + 0.5f) * s;
        const float px  = ((float)ix + 0.5f) * s;
        const float ddx = gcx - px;
        const float ddy = gcy - py;
        const float d   = sqrtf(ddx * ddx + ddy * ddy);
        key = ((unsigned long long)__float_as_uint(d) << 32) |
              (unsigned int)(base + iy * n + ix);
    }

    const float hx = s * 2.5f;
    #pragma unroll
    for (int q = 0; q < NTOPK; ++q) {
        const unsigned long long m = wave_min_u64_32(key);
        if (key == m) key = ~0ull;           // unique keys: one lane drops out

        // IoU for this slot (identical arithmetic; broadcast m -> all lanes same)
        const int idx  = (int)(m & 0xffffffffu);
        const int rel  = idx - base;
        const int iy   = rel / n;
        const int ix   = rel - iy * n;
        const float px = ((float)ix + 0.5f) * s;
        const float py = ((float)iy + 0.5f) * s;
        const float px0 = px - hx, py0 = py - hx;
        const float px1 = px + hx, py1 = py + hx;
        float lx = fmaxf(gt.x, px0), ly = fmaxf(gt.y, py0);
        float rx = fminf(gt.z, px1), ry = fminf(gt.w, py1);
        float w = fmaxf(rx - lx, 0.0f), h = fmaxf(ry - ly, 0.0f);
        float ovl = w * h;
        float parea = (px1 - px0) * (py1 - py0);
        float o = ovl / fmaxf(garea + parea - ovl, 1e-6f);  // EPS_OVERLAPS

        if (lane == 0) {                     // slot = L*9+q, ascending dist
            s_ov[L * NTOPK + q] = o;
            s_ix[L * NTOPK + q] = idx;
        }
    }
    __syncthreads();

    // thr: sequential slot-order sum + ddof=1 variance (bit-exact FP order)
    if (tid < NCAND) {
        float sum = 0.0f;
        for (int i = 0; i < NCAND; ++i) sum += s_ov[i];      // slot order
        const float mean = sum / (float)NCAND;
        float var = 0.0f;
        for (int i = 0; i < NCAND; ++i) {
            float d = s_ov[i] - mean;
            var += d * d;
        }
        const float thr = mean + sqrtf(var / (float)(NCAND - 1));  // std ddof=1

        // verdict for slot i = tid (identical constants/arithmetic)
        const int i = tid;
        unsigned int myval = 0xFFFFFFFFu;
        if (pad > 0.0f && s_ov[i] > thr) {
            const float si = (i < 9) ? 8.0f : (i < 18) ? 16.0f : 32.0f;
            const int   ni = (i < 9) ? 80   : (i < 18) ? 40    : 20;
            const int   bi = (i < 9) ? 0    : (i < 18) ? 6400  : 8000;
            const int idx = s_ix[i];
            const int rel = idx - bi;
            const int iy  = rel / ni;
            const int ix  = rel - iy * ni;
            const float px = ((float)ix + 0.5f) * si;  // == cell center (exact)
            const float py = ((float)iy + 0.5f) * si;
            // prior center strictly inside gt box (> 1e-9)
            float mm = fminf(fminf(px - gt.x, py - gt.y),
                             fminf(gt.z - px, gt.w - py));
            if (mm > 1e-9f) myval = (unsigned int)idx;
        }
        cand[(size_t)bg * NCAND + i] = myval;
    }
}

// ---------------------------------------------------------------------------
// Kernel 2: writer — EXACT R6 layout (33x32 blocks x 256, 256-prior tiles;
// best measured) + the R7-verified prefiltered invert (span-intersect test
// skips ~85% of candidate-list reads; conservative superset -> identical
// (g,p) OR-set -> masks bit-identical). Resolve + stores VERBATIM from the
// R1/R6-verified bodies (plain stores; nontemporal regressed earlier).
// ---------------------------------------------------------------------------
__global__ __launch_bounds__(256) void k_write(
    const float4* __restrict__ priors,
    const float4* __restrict__ gt_bboxes,
    const int*    __restrict__ gt_labels,
    const float4* __restrict__ pred_bboxes,
    const unsigned int* __restrict__ cand,
    float* __restrict__ out)
{
    __shared__ float4 s_gt[NG];
    __shared__ int    s_lab[NG];
    __shared__ unsigned long long s_pos[TILE];
    __shared__ int    s_plab[TILE];
    __shared__ float  s_piou[TILE];

    const int b   = blockIdx.y;
    const int tid = threadIdx.x;
    const int p0  = blockIdx.x * TILE;
    const int npr = min(TILE, NP - p0);        // 256, or 208 in the last tile

    if (tid < NG) {
        s_gt[tid]  = gt_bboxes[b * NG + tid];
        s_lab[tid] = gt_labels[b * NG + tid];
    }
    s_pos[tid] = 0;
    __syncthreads();

    // ---- prefiltered invert: (g = t>>2, level = t&3; 3 used) ----
    {
        const int g    = tid >> 2;
        const int part = tid & 3;              // 0..2 = level, 3 = idle
        if (part < 3) {
            const float s    = (part == 0) ? 8.0f : (part == 1) ? 16.0f : 32.0f;
            const int   n    = (part == 0) ? 80   : (part == 1) ? 40    : 20;
            const int   base = (part == 0) ? 0    : (part == 1) ? 6400  : 8000;
            const float4 gt  = s_gt[g];
            const float  gcx = (gt.x + gt.z) * 0.5f;
            const float  gcy = (gt.y + gt.w) * 0.5f;
            int wx = min(max((int)floorf(gcx / s) - 2, 0), n - 5);
            int wy = min(max((int)floorf(gcy / s) - 2, 0), n - 5);
            const int minidx = base + wy * n + wx;            // window span
            const int maxidx = base + (wy + 4) * n + wx + 4;  // (conservative)
            if (maxidx >= p0 && minidx < p0 + npr) {
                const unsigned int* e =
                    cand + ((size_t)(b * NG + g)) * NCAND + part * NTOPK;
                #pragma unroll
                for (int k = 0; k < NTOPK; ++k) {
                    unsigned int rel = e[k] - (unsigned int)p0;  // wraps if miss
                    if (rel < (unsigned int)npr)
                        atomicOr(&s_pos[rel], 1ull << g);
                }
            }
        }
    }
    __syncthreads();

    // ---- resolve + labels/bbox/fg (verbatim R1/R6 semantics) ----
    const int p = p0 + tid;
    int   label  = NUM_CLASSES;
    float iou_w  = 0.0f;

    if (p < NP) {
        const size_t bp = (size_t)b * NP + p;
        unsigned long long mask = s_pos[tid];
        int fg = __popcll(mask);
        int gidx = 0;

        if (fg > 1) {
            // conflict: argmax_g IoU(gt, prior_cell_box) over ALL gts, first
            // max wins (matches jnp.argmax(overlaps, axis=1) semantics).
            float4 pr = priors[p];
            float hx = pr.z * 2.5f, hy = pr.w * 2.5f;
            float px0 = pr.x - hx, py0 = pr.y - hy, px1 = pr.x + hx, py1 = pr.y + hy;
            float parea = (px1 - px0) * (py1 - py0);
            float best = -1.0f;
            for (int gg = 0; gg < NG; ++gg) {
                float4 gtb = s_gt[gg];
                float lx = fmaxf(gtb.x, px0), ly = fmaxf(gtb.y, py0);
                float rx = fminf(gtb.z, px1), ry = fminf(gtb.w, py1);
                float w = fmaxf(rx - lx, 0.0f), h = fmaxf(ry - ly, 0.0f);
                float ovl = w * h;
                float ga = (gtb.z - gtb.x) * (gtb.w - gtb.y);
                float v = ovl / fmaxf(ga + parea - ovl, 1e-6f);
                if (v > best) { best = v; gidx = gg; }
            }
        } else if (fg == 1) {
            gidx = __ffsll((unsigned long long)mask) - 1;
        }

        const bool   fgm = fg > 0;
        const float4 gtb = s_gt[gidx];   // gidx==0 for background (ref: argmax of zeros)
        label = fgm ? s_lab[gidx] : NUM_CLASSES;

        if (fgm) {
            float4 pb = pred_bboxes[bp];
            float lx = fmaxf(gtb.x, pb.x), ly = fmaxf(gtb.y, pb.y);
            float rx = fminf(gtb.z, pb.z), ry = fminf(gtb.w, pb.w);
            float w = fmaxf(rx - lx, 0.0f), h = fmaxf(ry - ly, 0.0f);
            float ov = w * h;
            float ga = (gtb.z - gtb.x) * (gtb.w - gtb.y);
            float pa = (pb.z - pb.x) * (pb.w - pb.y);
            iou_w = ov / (ga + pa - ov + 1e-9f);          // EPS_YOLOV6
        }

        out[bp] = (float)label;                           // labels
        ((float4*)(out + (size_t)BS * NP))[bp] = gtb;     // bboxes
        out[(size_t)BS * NP * 85 + bp] = fgm ? 1.0f : 0.0f;  // fg_mask
    }

    s_plab[tid] = label;
    s_piou[tid] = iou_w;
    __syncthreads();

    // ---- scores: [p0*80, (p0+npr)*80) floats of batch b -> coalesced f4 ----
    const int nfl4 = npr * 20;
    float4* o4 = (float4*)(out + (size_t)BS * NP * 5 + ((size_t)b * NP + p0) * 80);
    for (int q = tid; q < nfl4; q += 256) {
        int pl   = q / 20;          // local prior
        int comp = q - pl * 20;     // float4 slot within the 80-class row
        int lab  = s_plab[pl];
        float iw = s_piou[pl];
        int dd = lab - comp * 4;
        float4 v;
        v.x = (dd == 0) ? iw : 0.0f;
        v.y = (dd == 1) ? iw : 0.0f;
        v.z = (dd == 2) ? iw : 0.0f;
        v.w = (dd == 3) ? iw : 0.0f;
        o4[q] = v;
    }
}

extern "C" void kernel_launch(void* const* d_in, const int* in_sizes, int n_in,
                              void* d_out, int out_size, void* d_ws, size_t ws_size,
                              hipStream_t stream) {
    const float4* pred_bboxes = (const float4*)d_in[0];  // (32,8400,4) f32
    const float4* priors      = (const float4*)d_in[1];  // (8400,4)    f32
    const int*    gt_labels   = (const int*)d_in[2];     // (32,64,1)   i32
    const float4* gt_bboxes   = (const float4*)d_in[3];  // (32,64,4)   f32
    const float*  pad_flag    = (const float*)d_in[4];   // (32,64,1)   f32
    // d_in[5] = num_level_priors (6400,1600,400) — static, hard-coded.

    unsigned int* cand = (unsigned int*)d_ws;   // 221 KB, fully overwritten

    // TWO regular dispatches, no memset (best measured structure, R6).
    k_candidates<<<dim3(BS * NG), dim3(192), 0, stream>>>(
        gt_bboxes, pad_flag, cand);

    k_write<<<dim3(NTILE, BS), dim3(256), 0, stream>>>(
        priors, gt_bboxes, gt_labels, pred_bboxes, cand, (float*)d_out);
}